// Round 5
// baseline (633.300 us; speedup 1.0000x reference)
//
#include <hip/hip_runtime.h>

#define DECAY 0.8f
#define EPS   1e-5f
#define HN    8
#define BB    8
#define NSEQ  2048
#define DD    64
#define CC    1024
#define NROW  (BB*NSEQ)   /* 16384 rows per head */

#define XS(k,r) xs[(k)*128 + (r)]

typedef float vf4 __attribute__((ext_vector_type(4)));

// ---------------- kernel 1: row sum-of-squares for x and embed ----------------
__global__ void sumsq_kernel(const float* __restrict__ x, const float* __restrict__ embed,
                             float* __restrict__ fsq, float* __restrict__ esq) {
    int tid = blockIdx.x * blockDim.x + threadIdx.x;
    const int totalF = HN * NROW;
    const int totalE = HN * CC;
    if (tid < totalF) {
        const float4* src = (const float4*)(x + (size_t)tid * DD);
        float s = 0.f;
        #pragma unroll
        for (int i = 0; i < DD/4; ++i) {
            float4 v = src[i];
            s = fmaf(v.x, v.x, s); s = fmaf(v.y, v.y, s);
            s = fmaf(v.z, v.z, s); s = fmaf(v.w, v.w, s);
        }
        fsq[tid] = s;
    } else if (tid < totalF + totalE) {
        int t = tid - totalF;
        const float4* src = (const float4*)(embed + (size_t)t * DD);
        float s = 0.f;
        #pragma unroll
        for (int i = 0; i < DD/4; ++i) {
            float4 v = src[i];
            s = fmaf(v.x, v.x, s); s = fmaf(v.y, v.y, s);
            s = fmaf(v.z, v.z, s); s = fmaf(v.w, v.w, s);
        }
        esq[t] = s;
    }
}

// ---------------- kernel 1b: transpose embed [h][c][k] -> eT [h][k][c] ----------------
__global__ __launch_bounds__(256)
void transpose_kernel(const float* __restrict__ e, float* __restrict__ eT) {
    __shared__ float t[64][68];
    const int h  = blockIdx.y;
    const int c0 = blockIdx.x * 64;
    const float* eh  = e  + (size_t)h * CC * DD;
    float*       eTh = eT + (size_t)h * DD * CC;
    const int r = threadIdx.x >> 4;   // 0..15
    const int q = threadIdx.x & 15;   // 0..15

    #pragma unroll
    for (int rr = 0; rr < 4; ++rr) {
        int cl = rr*16 + r;
        float4 v = *(const float4*)(eh + (size_t)(c0 + cl)*DD + q*4);
        t[q*4+0][cl] = v.x; t[q*4+1][cl] = v.y; t[q*4+2][cl] = v.z; t[q*4+3][cl] = v.w;
    }
    __syncthreads();
    #pragma unroll
    for (int rr = 0; rr < 4; ++rr) {
        int k = rr*16 + r;
        float4 w = *(const float4*)&t[k][q*4];
        *(float4*)(eTh + (size_t)k*CC + c0 + q*4) = w;
    }
}

// ------------- kernel 2: fp32 dist GEMM (B from L2) + argmax + quantize + onehot + dist -------------
__global__ __launch_bounds__(512, 4)
void dist_fp32_kernel(const float* __restrict__ x, const float* __restrict__ embed,
                      const float* __restrict__ eT,
                      const float* __restrict__ fsq, const float* __restrict__ esq,
                      float* __restrict__ out_q, float* __restrict__ out_i,
                      float* __restrict__ out_oh, float* __restrict__ out_d) {
    __shared__ float xs[64 * 128];   // [k][row], transposed x tile, 32 KiB

    const int h   = blockIdx.y;
    const int n0  = blockIdx.x * 128;
    const int tid = threadIdx.x;
    const int ty  = tid >> 4;       // 0..31 -> rows ty*4 .. ty*4+3
    const int tx  = tid & 15;       // cols tx*8 .. tx*8+7 (within chunk)

    const float* xh_   = x     + (size_t)h * NROW * DD;
    const float* eh_   = embed + (size_t)h * CC   * DD;
    const float* eT_h  = eT    + (size_t)h * DD   * CC;
    const float* esq_h = esq   + h * CC;

    // ---- stage x tile (4x4 register transpose -> b128 LDS writes) ----
    {
        const int g4 = (tid & 31) * 4;  // 4 rows
        const int k0 = (tid >> 5) * 4;  // 4 k's
        float4 v[4];
        #pragma unroll
        for (int i = 0; i < 4; ++i)
            v[i] = *(const float4*)(xh_ + (size_t)(n0 + g4 + i) * DD + k0);
        *(float4*)&XS(k0+0, g4) = make_float4(v[0].x, v[1].x, v[2].x, v[3].x);
        *(float4*)&XS(k0+1, g4) = make_float4(v[0].y, v[1].y, v[2].y, v[3].y);
        *(float4*)&XS(k0+2, g4) = make_float4(v[0].z, v[1].z, v[2].z, v[3].z);
        *(float4*)&XS(k0+3, g4) = make_float4(v[0].w, v[1].w, v[2].w, v[3].w);
    }
    asm volatile("s_waitcnt lgkmcnt(0)" ::: "memory");
    __builtin_amdgcn_s_barrier();

    float fs[4];
    #pragma unroll
    for (int i = 0; i < 4; ++i) fs[i] = fsq[h*NROW + n0 + ty*4 + i];

    float bestv[4];
    int   besti[4];
    #pragma unroll
    for (int i = 0; i < 4; ++i) { bestv[i] = -3.4e38f; besti[i] = 0; }

    #pragma unroll 1
    for (int ci = 0; ci < 8; ++ci) {
        const int c0 = ci * 128;
        const float* bbase = eT_h + c0 + tx*8;

        float acc[4][8];
        #pragma unroll
        for (int i = 0; i < 4; ++i)
            #pragma unroll
            for (int j = 0; j < 8; ++j) acc[i][j] = 0.f;

        #pragma unroll 4
        for (int k = 0; k < 64; ++k) {
            float a[4], b[8];
            *(float4*)&a[0] = *(const float4*)&XS(k, ty*4);
            *(float4*)&b[0] = *(const float4*)(bbase + (size_t)k*CC);
            *(float4*)&b[4] = *(const float4*)(bbase + (size_t)k*CC + 4);
            #pragma unroll
            for (int i = 0; i < 4; ++i)
                #pragma unroll
                for (int j = 0; j < 8; ++j)
                    acc[i][j] = fmaf(a[i], b[j], acc[i][j]);
        }

        float eq[8];
        *(float4*)&eq[0] = *(const float4*)(esq_h + c0 + tx*8);
        *(float4*)&eq[4] = *(const float4*)(esq_h + c0 + tx*8 + 4);

        const vf4 z = {0.f, 0.f, 0.f, 0.f};
        #pragma unroll
        for (int i = 0; i < 4; ++i) {
            int row = n0 + ty*4 + i;
            float dv[8];
            #pragma unroll
            for (int j = 0; j < 8; ++j)
                dv[j] = fmaf(2.f, acc[i][j], -(fs[i] + eq[j]));

            size_t rb = ((size_t)h*NROW + row)*CC + c0 + tx*8;
            vf4 d0 = {dv[0], dv[1], dv[2], dv[3]};
            vf4 d1 = {dv[4], dv[5], dv[6], dv[7]};
            __builtin_nontemporal_store(d0, (vf4*)(out_d + rb));
            __builtin_nontemporal_store(d1, (vf4*)(out_d + rb + 4));
            __builtin_nontemporal_store(z,  (vf4*)(out_oh + rb));
            __builtin_nontemporal_store(z,  (vf4*)(out_oh + rb + 4));

            #pragma unroll
            for (int j = 0; j < 8; ++j) {
                if (dv[j] > bestv[i]) { bestv[i] = dv[j]; besti[i] = c0 + tx*8 + j; }
            }
        }
    }

    // drain this wave's one-hot zero stores before writing the 1.0s
    asm volatile("s_waitcnt vmcnt(0)" ::: "memory");

    // ---- argmax reduce across the 16 tx lanes sharing each row; write outputs ----
    #pragma unroll
    for (int i = 0; i < 4; ++i) {
        float v  = bestv[i];
        int   id = besti[i];
        #pragma unroll
        for (int off = 8; off >= 1; off >>= 1) {
            float ov = __shfl_xor(v, off, 64);
            int   oi = __shfl_xor(id, off, 64);
            if (ov > v || (ov == v && oi < id)) { v = ov; id = oi; }
        }
        int row = n0 + ty*4 + i;
        float4 qv = *(const float4*)(eh_ + (size_t)id*DD + tx*4);
        *(float4*)(out_q + ((size_t)h*NROW + row)*DD + tx*4) = qv;
        if (tx == 0) {
            out_i[(size_t)h*NROW + row] = (float)id;
            out_oh[((size_t)h*NROW + row)*CC + id] = 1.0f;
        }
    }
}

// ------------- kernel 3: deterministic EMA updates -------------
__global__ __launch_bounds__(64)
void ema_kernel(const float* __restrict__ x, const float* __restrict__ embed_avg,
                const float* __restrict__ cluster_size, const float* __restrict__ ind_f,
                float* __restrict__ out_cs, float* __restrict__ out_ea,
                float* __restrict__ out_norm) {
    const int h    = blockIdx.y;
    const int c    = blockIdx.x;
    const int lane = threadIdx.x;

    const float* cs_h = cluster_size + h*CC;
    float s = 0.f;
    #pragma unroll
    for (int i = 0; i < CC/64; ++i) s += cs_h[lane + i*64];
    #pragma unroll
    for (int off = 32; off >= 1; off >>= 1) s += __shfl_xor(s, off, 64);

    const float* xh   = x     + (size_t)h * NROW * DD;
    const float* indh = ind_f + (size_t)h * NROW;

    float sum_d = 0.f;
    int   cnt   = 0;
    for (int chunk = 0; chunk < NROW/64; ++chunk) {
        int myidx = (int)indh[chunk*64 + lane];
        unsigned long long m = __ballot(myidx == c);
        while (m) {
            int t = __ffsll(m) - 1;
            m &= m - 1;
            int n = chunk*64 + t;
            sum_d += xh[(size_t)n*DD + lane];
            cnt++;
        }
    }

    float csn  = cs_h[c]*DECAY + (float)cnt*(1.f - DECAY);
    float ea   = embed_avg[((size_t)h*CC + c)*DD + lane]*DECAY + sum_d*(1.f - DECAY);
    float ntot = s*DECAY + (1.f - DECAY)*(float)NROW;
    float css  = (csn + EPS) / (ntot + (float)CC*EPS) * ntot;

    out_ea  [((size_t)h*CC + c)*DD + lane] = ea;
    out_norm[((size_t)h*CC + c)*DD + lane] = ea / css;
    if (lane == 0) out_cs[h*CC + c] = csn;
}

extern "C" void kernel_launch(void* const* d_in, const int* in_sizes, int n_in,
                              void* d_out, int out_size, void* d_ws, size_t ws_size,
                              hipStream_t stream) {
    const float* x            = (const float*)d_in[0];
    const float* embed        = (const float*)d_in[1];
    const float* embed_avg    = (const float*)d_in[2];
    const float* cluster_size = (const float*)d_in[3];

    float* out = (float*)d_out;
    float* fsq = (float*)d_ws;
    float* esq = fsq + (size_t)HN * NROW;
    float* eT  = esq + (size_t)HN * CC;

    float* out_q    = out;
    float* out_i    = out_q    + (size_t)HN * NROW * DD;
    float* out_oh   = out_i    + (size_t)HN * NROW;
    float* out_d    = out_oh   + (size_t)HN * NROW * CC;
    float* out_norm = out_d    + (size_t)HN * NROW * CC;
    float* out_ea   = out_norm + (size_t)HN * CC * DD;
    float* out_cs   = out_ea   + (size_t)HN * CC * DD;

    {
        int total = HN*NROW + HN*CC;
        sumsq_kernel<<<(total + 255)/256, 256, 0, stream>>>(x, embed, fsq, esq);
    }
    {
        dim3 g(CC/64, HN);
        transpose_kernel<<<g, 256, 0, stream>>>(embed, eT);
    }
    {
        dim3 g(NROW/128, HN);
        dist_fp32_kernel<<<g, 512, 0, stream>>>(x, embed, eT, fsq, esq,
                                                out_q, out_i, out_oh, out_d);
    }
    {
        dim3 g(CC, HN);
        ema_kernel<<<g, 64, 0, stream>>>(x, embed_avg, cluster_size, out_i,
                                         out_cs, out_ea, out_norm);
    }
}

// Round 6
// 540.825 us; speedup vs baseline: 1.1710x; 1.1710x over previous
//
#include <hip/hip_runtime.h>

#define DECAY 0.8f
#define EPS   1e-5f
#define HN    8
#define BB    8
#define NSEQ  2048
#define DD    64
#define CC    1024
#define NROW  (BB*NSEQ)   /* 16384 rows per head */

#define LS 128            /* LDS row stride (floats) */
#define XS(k,r) xs[(k)*LS + (r)]
#define ES(k,c) es[(k)*LS + (c)]

typedef float vf4 __attribute__((ext_vector_type(4)));

// ---------------- kernel 1: row sum-of-squares for x and embed ----------------
__global__ void sumsq_kernel(const float* __restrict__ x, const float* __restrict__ embed,
                             float* __restrict__ fsq, float* __restrict__ esq) {
    int tid = blockIdx.x * blockDim.x + threadIdx.x;
    const int totalF = HN * NROW;
    const int totalE = HN * CC;
    if (tid < totalF) {
        const float4* src = (const float4*)(x + (size_t)tid * DD);
        float s = 0.f;
        #pragma unroll
        for (int i = 0; i < DD/4; ++i) {
            float4 v = src[i];
            s = fmaf(v.x, v.x, s); s = fmaf(v.y, v.y, s);
            s = fmaf(v.z, v.z, s); s = fmaf(v.w, v.w, s);
        }
        fsq[tid] = s;
    } else if (tid < totalF + totalE) {
        int t = tid - totalF;
        const float4* src = (const float4*)(embed + (size_t)t * DD);
        float s = 0.f;
        #pragma unroll
        for (int i = 0; i < DD/4; ++i) {
            float4 v = src[i];
            s = fmaf(v.x, v.x, s); s = fmaf(v.y, v.y, s);
            s = fmaf(v.z, v.z, s); s = fmaf(v.w, v.w, s);
        }
        esq[t] = s;
    }
}

// ------------- kernel 2: fp32 dist GEMM + argmax + quantize + onehot-1s + dist -------------
__global__ __launch_bounds__(256, 2)
void dist_fp32_kernel(const float* __restrict__ x, const float* __restrict__ embed,
                      const float* __restrict__ fsq, const float* __restrict__ esq,
                      float* __restrict__ out_q, float* __restrict__ out_i,
                      float* __restrict__ out_oh, float* __restrict__ out_d) {
    __shared__ float xs[64 * LS];   // [k][row], transposed x tile
    __shared__ float es[64 * LS];   // [k][col], transposed embed chunk

    const int h   = blockIdx.y;
    const int n0  = blockIdx.x * 128;
    const int tid = threadIdx.x;
    const int ty  = tid >> 4;       // 0..15 -> rows ty*8 .. ty*8+7
    const int tx  = tid & 15;       // cols {tx*4..+3} and {64+tx*4..+3}

    const float* xh_   = x     + (size_t)h * NROW * DD;
    const float* eh_   = embed + (size_t)h * CC   * DD;
    const float* esq_h = esq   + h * CC;

    const int g4 = (tid & 31) * 4;  // group of 4 rows/cols to transpose
    const int k0 = (tid >> 5) * 8;  // group of 8 k's

    // ---- stage x tile (4x4 register transpose -> b128 LDS writes) ----
    {
        float4 v[2][4];
        #pragma unroll
        for (int t = 0; t < 2; ++t)
            #pragma unroll
            for (int i = 0; i < 4; ++i)
                v[t][i] = *(const float4*)(xh_ + (size_t)(n0 + g4 + i) * DD + k0 + t*4);
        #pragma unroll
        for (int t = 0; t < 2; ++t) {
            *(float4*)&XS(k0+t*4+0, g4) = make_float4(v[t][0].x, v[t][1].x, v[t][2].x, v[t][3].x);
            *(float4*)&XS(k0+t*4+1, g4) = make_float4(v[t][0].y, v[t][1].y, v[t][2].y, v[t][3].y);
            *(float4*)&XS(k0+t*4+2, g4) = make_float4(v[t][0].z, v[t][1].z, v[t][2].z, v[t][3].z);
            *(float4*)&XS(k0+t*4+3, g4) = make_float4(v[t][0].w, v[t][1].w, v[t][2].w, v[t][3].w);
        }
    }
    // ---- stage embed chunk 0 ----
    {
        float4 v[2][4];
        #pragma unroll
        for (int t = 0; t < 2; ++t)
            #pragma unroll
            for (int i = 0; i < 4; ++i)
                v[t][i] = *(const float4*)(eh_ + (size_t)(g4 + i) * DD + k0 + t*4);
        #pragma unroll
        for (int t = 0; t < 2; ++t) {
            *(float4*)&ES(k0+t*4+0, g4) = make_float4(v[t][0].x, v[t][1].x, v[t][2].x, v[t][3].x);
            *(float4*)&ES(k0+t*4+1, g4) = make_float4(v[t][0].y, v[t][1].y, v[t][2].y, v[t][3].y);
            *(float4*)&ES(k0+t*4+2, g4) = make_float4(v[t][0].z, v[t][1].z, v[t][2].z, v[t][3].z);
            *(float4*)&ES(k0+t*4+3, g4) = make_float4(v[t][0].w, v[t][1].w, v[t][2].w, v[t][3].w);
        }
    }
    asm volatile("s_waitcnt lgkmcnt(0)" ::: "memory");
    __builtin_amdgcn_s_barrier();

    float fs[8];
    #pragma unroll
    for (int i = 0; i < 8; ++i) fs[i] = fsq[h*NROW + n0 + ty*8 + i];

    float bestv[8];
    int   besti[8];
    #pragma unroll
    for (int i = 0; i < 8; ++i) { bestv[i] = -3.4e38f; besti[i] = 0; }

    #pragma unroll 1
    for (int ci = 0; ci < 8; ++ci) {
        const int c0 = ci * 128;

        // prefetch next chunk into registers (flies under the FMA phase)
        float4 ev[2][4];
        if (ci < 7) {
            #pragma unroll
            for (int t = 0; t < 2; ++t)
                #pragma unroll
                for (int i = 0; i < 4; ++i)
                    ev[t][i] = *(const float4*)(eh_ + (size_t)(c0 + 128 + g4 + i) * DD + k0 + t*4);
        }

        float acc[8][8];
        #pragma unroll
        for (int i = 0; i < 8; ++i)
            #pragma unroll
            for (int j = 0; j < 8; ++j) acc[i][j] = 0.f;

        #pragma unroll 4
        for (int k = 0; k < 64; ++k) {
            float a[8], b[8];
            *(float4*)&a[0] = *(const float4*)&XS(k, ty*8);
            *(float4*)&a[4] = *(const float4*)&XS(k, ty*8 + 4);
            *(float4*)&b[0] = *(const float4*)&ES(k, tx*4);
            *(float4*)&b[4] = *(const float4*)&ES(k, 64 + tx*4);
            #pragma unroll
            for (int i = 0; i < 8; ++i)
                #pragma unroll
                for (int j = 0; j < 8; ++j)
                    acc[i][j] = fmaf(a[i], b[j], acc[i][j]);
        }

        float eq[8];
        *(float4*)&eq[0] = *(const float4*)(esq_h + c0 + tx*4);
        *(float4*)&eq[4] = *(const float4*)(esq_h + c0 + 64 + tx*4);

        #pragma unroll
        for (int i = 0; i < 8; ++i) {
            int row = n0 + ty*8 + i;
            float dv[8];
            #pragma unroll
            for (int j = 0; j < 8; ++j)
                dv[j] = fmaf(2.f, acc[i][j], -(fs[i] + eq[j]));

            size_t rb = ((size_t)h*NROW + row)*CC + c0;
            vf4 d0 = {dv[0], dv[1], dv[2], dv[3]};
            vf4 d1 = {dv[4], dv[5], dv[6], dv[7]};
            __builtin_nontemporal_store(d0, (vf4*)(out_d + rb + tx*4));
            __builtin_nontemporal_store(d1, (vf4*)(out_d + rb + 64 + tx*4));

            #pragma unroll
            for (int j = 0; j < 4; ++j) {
                if (dv[j] > bestv[i]) { bestv[i] = dv[j]; besti[i] = c0 + tx*4 + j; }
            }
            #pragma unroll
            for (int j = 4; j < 8; ++j) {
                if (dv[j] > bestv[i]) { bestv[i] = dv[j]; besti[i] = c0 + 64 + tx*4 + (j-4); }
            }
        }

        if (ci < 7) {
            // all waves done reading es (lgkmcnt==0 covers LDS reads)
            asm volatile("s_waitcnt lgkmcnt(0)" ::: "memory");
            __builtin_amdgcn_s_barrier();
            #pragma unroll
            for (int t = 0; t < 2; ++t) {
                *(float4*)&ES(k0+t*4+0, g4) = make_float4(ev[t][0].x, ev[t][1].x, ev[t][2].x, ev[t][3].x);
                *(float4*)&ES(k0+t*4+1, g4) = make_float4(ev[t][0].y, ev[t][1].y, ev[t][2].y, ev[t][3].y);
                *(float4*)&ES(k0+t*4+2, g4) = make_float4(ev[t][0].z, ev[t][1].z, ev[t][2].z, ev[t][3].z);
                *(float4*)&ES(k0+t*4+3, g4) = make_float4(ev[t][0].w, ev[t][1].w, ev[t][2].w, ev[t][3].w);
            }
            asm volatile("s_waitcnt lgkmcnt(0)" ::: "memory");
            __builtin_amdgcn_s_barrier();
        }
    }

    // onehot zeros were written by the stream-ordered memset before this kernel;
    // each (row, id) cell is written exactly once here -> no drain needed.

    // ---- argmax reduce across the 16 tx lanes sharing each row; write outputs ----
    #pragma unroll
    for (int i = 0; i < 8; ++i) {
        float v  = bestv[i];
        int   id = besti[i];
        #pragma unroll
        for (int off = 8; off >= 1; off >>= 1) {
            float ov = __shfl_xor(v, off, 64);
            int   oi = __shfl_xor(id, off, 64);
            if (ov > v || (ov == v && oi < id)) { v = ov; id = oi; }
        }
        int row = n0 + ty*8 + i;
        float4 qv = *(const float4*)(eh_ + (size_t)id*DD + tx*4);
        *(float4*)(out_q + ((size_t)h*NROW + row)*DD + tx*4) = qv;
        if (tx == 0) {
            out_i[(size_t)h*NROW + row] = (float)id;
            out_oh[((size_t)h*NROW + row)*CC + id] = 1.0f;
        }
    }
}

// ------------- kernel 3: deterministic EMA updates -------------
__global__ __launch_bounds__(64)
void ema_kernel(const float* __restrict__ x, const float* __restrict__ embed_avg,
                const float* __restrict__ cluster_size, const float* __restrict__ ind_f,
                float* __restrict__ out_cs, float* __restrict__ out_ea,
                float* __restrict__ out_norm) {
    const int h    = blockIdx.y;
    const int c    = blockIdx.x;
    const int lane = threadIdx.x;

    const float* cs_h = cluster_size + h*CC;
    float s = 0.f;
    #pragma unroll
    for (int i = 0; i < CC/64; ++i) s += cs_h[lane + i*64];
    #pragma unroll
    for (int off = 32; off >= 1; off >>= 1) s += __shfl_xor(s, off, 64);

    const float* xh   = x     + (size_t)h * NROW * DD;
    const float* indh = ind_f + (size_t)h * NROW;

    float sum_d = 0.f;
    int   cnt   = 0;
    for (int chunk = 0; chunk < NROW/64; ++chunk) {
        int myidx = (int)indh[chunk*64 + lane];
        unsigned long long m = __ballot(myidx == c);
        while (m) {
            int t = __ffsll(m) - 1;
            m &= m - 1;
            int n = chunk*64 + t;
            sum_d += xh[(size_t)n*DD + lane];
            cnt++;
        }
    }

    float csn  = cs_h[c]*DECAY + (float)cnt*(1.f - DECAY);
    float ea   = embed_avg[((size_t)h*CC + c)*DD + lane]*DECAY + sum_d*(1.f - DECAY);
    float ntot = s*DECAY + (1.f - DECAY)*(float)NROW;
    float css  = (csn + EPS) / (ntot + (float)CC*EPS) * ntot;

    out_ea  [((size_t)h*CC + c)*DD + lane] = ea;
    out_norm[((size_t)h*CC + c)*DD + lane] = ea / css;
    if (lane == 0) out_cs[h*CC + c] = csn;
}

extern "C" void kernel_launch(void* const* d_in, const int* in_sizes, int n_in,
                              void* d_out, int out_size, void* d_ws, size_t ws_size,
                              hipStream_t stream) {
    const float* x            = (const float*)d_in[0];
    const float* embed        = (const float*)d_in[1];
    const float* embed_avg    = (const float*)d_in[2];
    const float* cluster_size = (const float*)d_in[3];

    float* out = (float*)d_out;
    float* fsq = (float*)d_ws;
    float* esq = fsq + (size_t)HN * NROW;

    float* out_q    = out;
    float* out_i    = out_q    + (size_t)HN * NROW * DD;
    float* out_oh   = out_i    + (size_t)HN * NROW;
    float* out_d    = out_oh   + (size_t)HN * NROW * CC;
    float* out_norm = out_d    + (size_t)HN * NROW * CC;
    float* out_ea   = out_norm + (size_t)HN * CC * DD;
    float* out_cs   = out_ea   + (size_t)HN * CC * DD;

    // zero the one-hot output with a pure-BW fill (stream-ordered before k2)
    hipMemsetAsync(out_oh, 0, (size_t)HN * NROW * CC * sizeof(float), stream);

    {
        int total = HN*NROW + HN*CC;
        sumsq_kernel<<<(total + 255)/256, 256, 0, stream>>>(x, embed, fsq, esq);
    }
    {
        dim3 g(NROW/128, HN);
        dist_fp32_kernel<<<g, 256, 0, stream>>>(x, embed, fsq, esq,
                                                out_q, out_i, out_oh, out_d);
    }
    {
        dim3 g(CC, HN);
        ema_kernel<<<g, 64, 0, stream>>>(x, embed_avg, cluster_size, out_i,
                                         out_cs, out_ea, out_norm);
    }
}